// Round 11
// baseline (54.815 us; speedup 1.0000x reference)
//
#include <hip/hip_runtime.h>

// Depthwise xcorr: out[p][oy][ox] = sum_{ky,kx} x[p][oy+ky][ox+kx] * z[p][ky][kx]
// 32768 planes. x: 31x31, z: 7x7, out: 25x25, fp32.
//
// Round 11: persistent depth-1 double-buffered pipeline (T3-minimum), with
// the two confounds of R8/R9 removed:
//  - z staged in LDS (zr-from-global caused the R7/R9 scratch spills)
//  - 16B global_load_lds staging (10 dwordx4 chunks vs 52 dword chunks);
//    tile base not 16B-aligned -> stage from g0 = xoff & ~3 and read LDS at
//    off0 = xoff & 3 (pad slots hold stream data, so every read is correct)
//  - packed stride-31 LDS (conflicts proven non-critical in R5/R6/R10)
//  - buffer = 4808 x-dwords + 256 z-dwords = 5064; LDS 2*5064*4 = 40512 B
//    -> 4 blocks/CU (8 waves), each persistent block loops ~6.4 tiles:
//    STAGE(next, buf^1) BEFORE compute(buf); one __syncthreads per tile, so
//    the vmcnt(0) drain lands after a ~2800-cycle compute phase.

#define PPB 5
#define WX 31
#define XPLANE 961
#define TDW (PPB * XPLANE)       // 4805 x dwords per tile
#define XREG 4808                // x region dwords per buffer
#define ZREG 256
#define BUFDW (XREG + ZREG)      // 5064
#define ZPLANE 49
#define OPLANE 625
#define WO 25
#define GRID 1024                // 4 persistent blocks per CU

typedef __attribute__((address_space(1))) const void gaddr_t;
typedef __attribute__((address_space(3))) void laddr_t;

__global__ __launch_bounds__(128, 2) void dwxcorr_kernel(
    const float* __restrict__ z, const float* __restrict__ x,
    float* __restrict__ out, int nplanes, int ntiles) {
  __shared__ float xs[2][BUFDW];  // 40512 B -> 4 blocks/CU

  const int tid = threadIdx.x;
  const int wbase = tid & ~63;          // wave-uniform dword base (4B chunks)
  const int wbase4 = (tid & ~63) * 4;   // wave-uniform dword base (16B chunks)
  const long XTOT = (long)nplanes * XPLANE;
  const long ZTOT = (long)nplanes * ZPLANE;

  const int cpp = tid / 25;             // plane within tile (0..4 for tid<125)
  const int t25 = tid - cpp * 25;
  const int ty = t25 / 5;
  const int tx = t25 - ty * 5;
  const int tx5 = tx * 5;
  const bool act0 = (tid < PPB * 25);   // 125/128 lanes compute

  // Stage tile -> buffer: LDS[s] = x[g0 + s] for s in [0, XREG), then z.
  auto STAGE = [&](int buf, int tile) {
    const long xoff = (long)tile * TDW;      // first dword of tile
    const long g0 = xoff & ~3L;              // 16B-aligned stream base
#pragma unroll
    for (int c = 0; c < 10; ++c) {
      if (c < 9 || tid < 50) {               // chunk 9 partial: slots 4608..4807
        long gd = g0 + c * 512 + tid * 4;    // lane reads 4 dwords (16B)
        if (gd > XTOT - 4) gd = XTOT - 4;    // aligned tail clamp (dup, unread)
        __builtin_amdgcn_global_load_lds((gaddr_t*)(x + gd),
                                         (laddr_t*)&xs[buf][c * 512 + wbase4],
                                         16, 0, 0);
      }
    }
    const long zoff = (long)tile * (PPB * ZPLANE);
#pragma unroll
    for (int c = 0; c < 2; ++c) {
      long gz = zoff + c * 128 + tid;
      if (gz >= ZTOT) gz = ZTOT - 1;         // dup, never read
      __builtin_amdgcn_global_load_lds((gaddr_t*)(z + gz),
                                       (laddr_t*)&xs[buf][XREG + c * 128 + wbase],
                                       4, 0, 0);
    }
  };

  const int bstart = blockIdx.x;
  if (bstart >= ntiles) return;

  STAGE(0, bstart);
  __syncthreads();  // prologue drain

  int cur = 0;
  for (int t = bstart; t < ntiles; t += GRID) {
    const int tn = t + GRID;
    if (tn < ntiles) STAGE(cur ^ 1, tn);  // prefetch: in flight through compute

    const int p0 = t * PPB;
    const int pmax = min(PPB, nplanes - p0);
    if (act0 && cpp < pmax) {
      const int off0 = (int)(((long)t * TDW) & 3);  // xoff - g0

      const float* zb = &xs[cur][XREG + cpp * ZPLANE];
      float zr[ZPLANE];
#pragma unroll
      for (int j = 0; j < ZPLANE; ++j) zr[j] = zb[j];

      float acc[5][5];
#pragma unroll
      for (int r = 0; r < 5; ++r)
#pragma unroll
        for (int j2 = 0; j2 < 5; ++j2) acc[r][j2] = 0.0f;

      const float* pb = &xs[cur][off0 + cpp * XPLANE + (ty * 5) * WX + tx5];

#pragma unroll
      for (int iy = 0; iy < 11; ++iy) {
        float xr[11];
#pragma unroll
        for (int k = 0; k < 11; ++k) xr[k] = pb[iy * WX + k];
        const int ky_lo = (iy - 4 < 0) ? 0 : iy - 4;
        const int ky_hi = (iy < 6) ? iy : 6;
#pragma unroll
        for (int ky = 0; ky < 7; ++ky) {
          if (ky < ky_lo || ky > ky_hi) continue;  // folds at compile time
          const int orow = iy - ky;
#pragma unroll
          for (int kx = 0; kx < 7; ++kx) {
            const float zv = zr[ky * 7 + kx];
#pragma unroll
            for (int j2 = 0; j2 < 5; ++j2)
              acc[orow][j2] = fmaf(xr[kx + j2], zv, acc[orow][j2]);
          }
        }
      }

      float* ob = out + (long)(p0 + cpp) * OPLANE + (ty * 5) * WO + tx5;
#pragma unroll
      for (int r = 0; r < 5; ++r)
#pragma unroll
        for (int j2 = 0; j2 < 5; ++j2) ob[r * WO + j2] = acc[r][j2];
    }

    __syncthreads();  // drains prefetch (after full compute) + protects swap
    cur ^= 1;
  }
}

extern "C" void kernel_launch(void* const* d_in, const int* in_sizes, int n_in,
                              void* d_out, int out_size, void* d_ws, size_t ws_size,
                              hipStream_t stream) {
  const float* z = (const float*)d_in[0];  // [B,C,7,7]
  const float* x = (const float*)d_in[1];  // [B,C,31,31]
  float* out = (float*)d_out;              // [B,C,25,25]

  const int nplanes = in_sizes[0] / ZPLANE;        // 32768
  const int ntiles = (nplanes + PPB - 1) / PPB;    // 6554

  hipLaunchKernelGGL(dwxcorr_kernel, dim3(GRID), dim3(128), 0, stream,
                     z, x, out, nplanes, ntiles);
}

// Round 13
// 54.316 us; speedup vs baseline: 1.0092x; 1.0092x over previous
//
#include <hip/hip_runtime.h>

// Depthwise xcorr: out[p][oy][ox] = sum_{ky,kx} x[p][oy+ky][ox+kx] * z[p][ky][kx]
// 32768 planes. x: 31x31, z: 7x7, out: 25x25, fp32.
//
// Round 13 = round 12 resubmitted (UnresponsiveContainer ate the bench).
// Occupancy-first consolidation. Cross-round analysis (R5/R10/R11):
// timed perf is monotone in waves/SIMD (4 > 3 > 2) at equal lane efficiency;
// conflicts and intra-block pipelining are secondary. This round keeps R5's
// winning ingredients (packed linear staging, z in LDS, 97.7% lanes, 4
// waves/SIMD) and doubles the number of independent blocks per CU:
//  - 128-thread blocks, PPB=5, LDS = (4864+256)*4 = 20480 B exactly
//    -> 8 blocks/CU x 2 waves = 16 waves/CU (4/SIMD), fine-grained
//    stage/compute overlap across 8 independent blocks.
//  - packed stride-31 LDS, linear async global_load_lds staging (gi = xoff+s,
//    ~1 VALU/chunk); uniform fast path for non-tail blocks (no clamps).
//  - z staged to LDS (global-held zr caused R7/R9 spills).
//  - __launch_bounds__(128,4): VGPR cap 128, no spill (R10: 88 VGPR).

#define PPB 5
#define WX 31
#define XPLANE 961
#define TDW (PPB * XPLANE)     // 4805 x dwords per block
#define XCH 38                 // ceil(4805/128)
#define XREG (XCH * 128)       // 4864 dwords (59-slot pad, dup data)
#define ZPLANE 49
#define ZDW (PPB * ZPLANE)     // 245
#define ZREG 256
#define OPLANE 625
#define WO 25

typedef __attribute__((address_space(1))) const void gaddr_t;
typedef __attribute__((address_space(3))) void laddr_t;

__global__ __launch_bounds__(128, 4) void dwxcorr_kernel(
    const float* __restrict__ z, const float* __restrict__ x,
    float* __restrict__ out, int nplanes) {
  __shared__ float xs[XREG];  // 19456 B, packed stride-31 planes
  __shared__ float zs[ZREG];  //  1024 B -> 20480 B total -> 8 blocks/CU

  const int tid = threadIdx.x;
  const int wbase = tid & ~63;   // wave-uniform LDS chunk base
  const int p0 = blockIdx.x * PPB;
  const int pmax = min(PPB, nplanes - p0);
  const long xoff = (long)p0 * XPLANE;
  const long zoff = (long)p0 * ZPLANE;

  if (pmax == PPB && (long)(blockIdx.x + 1) * TDW + 59 <= (long)nplanes * XPLANE) {
    // ---- fast path (6553 of 6554 blocks): no clamping at all ----
#pragma unroll
    for (int c = 0; c < XCH; ++c)
      __builtin_amdgcn_global_load_lds((gaddr_t*)(x + xoff + c * 128 + tid),
                                       (laddr_t*)&xs[c * 128 + wbase], 4, 0, 0);
#pragma unroll
    for (int c = 0; c < 2; ++c) {
      long gz = zoff + c * 128 + tid;
      long zmax = (long)nplanes * ZPLANE - 1;
      if (gz > zmax) gz = zmax;  // only trips in the very last blocks
      __builtin_amdgcn_global_load_lds((gaddr_t*)(z + gz),
                                       (laddr_t*)&zs[c * 128 + wbase], 4, 0, 0);
    }
  } else {
    // ---- tail block: clamp everything (dup data, never read) ----
    const long xmax = (long)nplanes * XPLANE - 1;
    const long zmax = (long)nplanes * ZPLANE - 1;
#pragma unroll
    for (int c = 0; c < XCH; ++c) {
      long gi = xoff + c * 128 + tid;
      if (gi > xmax) gi = xmax;
      __builtin_amdgcn_global_load_lds((gaddr_t*)(x + gi),
                                       (laddr_t*)&xs[c * 128 + wbase], 4, 0, 0);
    }
#pragma unroll
    for (int c = 0; c < 2; ++c) {
      long gz = zoff + c * 128 + tid;
      if (gz > zmax) gz = zmax;
      __builtin_amdgcn_global_load_lds((gaddr_t*)(z + gz),
                                       (laddr_t*)&zs[c * 128 + wbase], 4, 0, 0);
    }
  }
  __syncthreads();  // single drain + barrier

  // ---- compute: thread -> (plane cpp, 5x5 tile (ty,tx)); 125/128 active ----
  const int cpp = tid / 25;
  if (tid >= PPB * 25 || cpp >= pmax) return;
  const int t25 = tid - cpp * 25;
  const int ty = t25 / 5;
  const int tx = t25 - ty * 5;
  const int tx5 = tx * 5;

  // z from LDS (compiler sinks each read to first use; no spill)
  float zr[ZPLANE];
#pragma unroll
  for (int j = 0; j < ZPLANE; ++j) zr[j] = zs[cpp * ZPLANE + j];

  float acc[5][5];
#pragma unroll
  for (int r = 0; r < 5; ++r)
#pragma unroll
    for (int j = 0; j < 5; ++j) acc[r][j] = 0.0f;

  const float* pb = &xs[cpp * XPLANE + (ty * 5) * WX + tx5];

  // Stream 11 patch rows; row iy feeds output rows orow = iy-ky in [0,4]
#pragma unroll
  for (int iy = 0; iy < 11; ++iy) {
    float xr[11];
#pragma unroll
    for (int k = 0; k < 11; ++k) xr[k] = pb[iy * WX + k];
    const int ky_lo = (iy - 4 < 0) ? 0 : iy - 4;
    const int ky_hi = (iy < 6) ? iy : 6;
#pragma unroll
    for (int ky = 0; ky < 7; ++ky) {
      if (ky < ky_lo || ky > ky_hi) continue;  // folds at compile time
      const int orow = iy - ky;
#pragma unroll
      for (int kx = 0; kx < 7; ++kx) {
        const float zv = zr[ky * 7 + kx];
#pragma unroll
        for (int j = 0; j < 5; ++j)
          acc[orow][j] = fmaf(xr[kx + j], zv, acc[orow][j]);
      }
    }
  }

  // ---- write the 5x5 tile ----
  float* ob = out + (long)(p0 + cpp) * OPLANE + (ty * 5) * WO + tx5;
#pragma unroll
  for (int r = 0; r < 5; ++r)
#pragma unroll
    for (int j = 0; j < 5; ++j) ob[r * WO + j] = acc[r][j];
}

extern "C" void kernel_launch(void* const* d_in, const int* in_sizes, int n_in,
                              void* d_out, int out_size, void* d_ws, size_t ws_size,
                              hipStream_t stream) {
  const float* z = (const float*)d_in[0];  // [B,C,7,7]
  const float* x = (const float*)d_in[1];  // [B,C,31,31]
  float* out = (float*)d_out;              // [B,C,25,25]

  const int nplanes = in_sizes[0] / ZPLANE;      // 32768
  const int blocks = (nplanes + PPB - 1) / PPB;  // 6554

  hipLaunchKernelGGL(dwxcorr_kernel, dim3(blocks), dim3(128), 0, stream,
                     z, x, out, nplanes);
}

// Round 14
// 47.986 us; speedup vs baseline: 1.1423x; 1.1319x over previous
//
#include <hip/hip_runtime.h>

// Depthwise xcorr: out[p][oy][ox] = sum_{ky,kx} x[p][oy+ky][ox+kx] * z[p][ky][kx]
// 32768 planes. x: 31x31, z: 7x7, out: 25x25, fp32.
//
// Round 14: R5's best config (50.7us: 256thr, PPB=10, 4 blocks/CU, one-shot,
// z in LDS, packed stride-31) + 16-byte global_load_lds staging (the one
// proven-mechanism lever never tested in this config; 4x fewer stage
// instructions and HBM requests -> shrinks the per-block serial stage window
// that the 50-55us plateau is made of).
//  - tile x base (9610*t dwords) not 16B-aligned: stage from g0 = base & ~3,
//    read LDS at off0 = base & 3 (0 or 2). Same for z (490*t dwords).
//  - LDS = (9616 + 496)*4 = 40448 B -> 4 blocks/CU with allocator margin.
//  - plain __launch_bounds__(256): R13's (128,4) made the compiler cap VGPR
//    at 64 and spill (+28MB HBM); R5's plain bound gave VGPR=68, no spill.

#define PPB 10
#define WX 31
#define XPLANE 961
#define TDW (PPB * XPLANE)     // 9610 x dwords per tile
#define XREG 9616              // staged x dwords (16B multiple)
#define ZPLANE 49
#define ZDW (PPB * ZPLANE)     // 490
#define ZREG 496               // staged z dwords (16B multiple)
#define OPLANE 625
#define WO 25

typedef __attribute__((address_space(1))) const void gaddr_t;
typedef __attribute__((address_space(3))) void laddr_t;

__global__ __launch_bounds__(256) void dwxcorr_kernel(
    const float* __restrict__ z, const float* __restrict__ x,
    float* __restrict__ out, int nplanes, int ntiles) {
  __shared__ float lds[XREG + ZREG];  // 40448 B -> 4 blocks/CU

  const int tid = threadIdx.x;
  const int t = blockIdx.x;
  const int wb4 = (tid & ~63) * 4;    // wave-uniform LDS dword base (16B/lane)
  const long XTOT = (long)nplanes * XPLANE;  // 31490048 (16B-aligned count)
  const long ZTOT = (long)nplanes * ZPLANE;  // 1605632

  const long xoff = (long)t * TDW;
  const long g0 = xoff & ~3L;
  const int off0 = (int)(xoff & 3);
  const long zoff = (long)t * ZDW;
  const long gz0 = zoff & ~3L;
  const int offz = (int)(zoff & 3);

  if (g0 + XREG <= XTOT && gz0 + ZREG <= ZTOT) {
    // ---- fast path: no clamping ----
#pragma unroll
    for (int c = 0; c < 9; ++c)  // 9 full chunks: dwords [c*1024, c*1024+1024)
      __builtin_amdgcn_global_load_lds((gaddr_t*)(x + g0 + c * 1024 + tid * 4),
                                       (laddr_t*)&lds[c * 1024 + wb4], 16, 0, 0);
    if (tid < 100)               // partial chunk: dwords [9216, 9616)
      __builtin_amdgcn_global_load_lds((gaddr_t*)(x + g0 + 9216 + tid * 4),
                                       (laddr_t*)&lds[9216 + wb4], 16, 0, 0);
    if (tid < 124)               // z: dwords [0, 496) of region
      __builtin_amdgcn_global_load_lds((gaddr_t*)(z + gz0 + tid * 4),
                                       (laddr_t*)&lds[XREG + wb4], 16, 0, 0);
  } else {
    // ---- tail block: clamp to last aligned 16B (dup data, never read) ----
#pragma unroll
    for (int c = 0; c < 9; ++c) {
      long gd = g0 + c * 1024 + tid * 4;
      if (gd > XTOT - 4) gd = XTOT - 4;
      __builtin_amdgcn_global_load_lds((gaddr_t*)(x + gd),
                                       (laddr_t*)&lds[c * 1024 + wb4], 16, 0, 0);
    }
    if (tid < 100) {
      long gd = g0 + 9216 + tid * 4;
      if (gd > XTOT - 4) gd = XTOT - 4;
      __builtin_amdgcn_global_load_lds((gaddr_t*)(x + gd),
                                       (laddr_t*)&lds[9216 + wb4], 16, 0, 0);
    }
    if (tid < 124) {
      long gd = gz0 + tid * 4;
      if (gd > ZTOT - 4) gd = ZTOT - 4;
      __builtin_amdgcn_global_load_lds((gaddr_t*)(z + gd),
                                       (laddr_t*)&lds[XREG + wb4], 16, 0, 0);
    }
  }
  __syncthreads();  // single drain + barrier

  // ---- compute: thread -> (plane cpp, 5x5 tile (ty,tx)); 250/256 active ----
  const int p0 = t * PPB;
  const int pmax = min(PPB, nplanes - p0);
  const int cpp = tid / 25;
  if (tid >= PPB * 25 || cpp >= pmax) return;
  const int t25 = tid - cpp * 25;
  const int ty = t25 / 5;
  const int tx = t25 - ty * 5;
  const int tx5 = tx * 5;

  // z from LDS (compiler sinks each read to first use; no spill)
  const float* zb = &lds[XREG + offz + cpp * ZPLANE];
  float zr[ZPLANE];
#pragma unroll
  for (int j = 0; j < ZPLANE; ++j) zr[j] = zb[j];

  float acc[5][5];
#pragma unroll
  for (int r = 0; r < 5; ++r)
#pragma unroll
    for (int j = 0; j < 5; ++j) acc[r][j] = 0.0f;

  const float* pb = &lds[off0 + cpp * XPLANE + (ty * 5) * WX + tx5];

  // Stream 11 patch rows; row iy feeds output rows orow = iy-ky in [0,4]
#pragma unroll
  for (int iy = 0; iy < 11; ++iy) {
    float xr[11];
#pragma unroll
    for (int k = 0; k < 11; ++k) xr[k] = pb[iy * WX + k];
    const int ky_lo = (iy - 4 < 0) ? 0 : iy - 4;
    const int ky_hi = (iy < 6) ? iy : 6;
#pragma unroll
    for (int ky = 0; ky < 7; ++ky) {
      if (ky < ky_lo || ky > ky_hi) continue;  // folds at compile time
      const int orow = iy - ky;
#pragma unroll
      for (int kx = 0; kx < 7; ++kx) {
        const float zv = zr[ky * 7 + kx];
#pragma unroll
        for (int j = 0; j < 5; ++j)
          acc[orow][j] = fmaf(xr[kx + j], zv, acc[orow][j]);
      }
    }
  }

  // ---- write the 5x5 tile ----
  float* ob = out + (long)(p0 + cpp) * OPLANE + (ty * 5) * WO + tx5;
#pragma unroll
  for (int r = 0; r < 5; ++r)
#pragma unroll
    for (int j = 0; j < 5; ++j) ob[r * WO + j] = acc[r][j];
}

extern "C" void kernel_launch(void* const* d_in, const int* in_sizes, int n_in,
                              void* d_out, int out_size, void* d_ws, size_t ws_size,
                              hipStream_t stream) {
  const float* z = (const float*)d_in[0];  // [B,C,7,7]
  const float* x = (const float*)d_in[1];  // [B,C,31,31]
  float* out = (float*)d_out;              // [B,C,25,25]

  const int nplanes = in_sizes[0] / ZPLANE;        // 32768
  const int ntiles = (nplanes + PPB - 1) / PPB;    // 3277

  hipLaunchKernelGGL(dwxcorr_kernel, dim3(ntiles), dim3(256), 0, stream,
                     z, x, out, nplanes, ntiles);
}

// Round 15
// 45.473 us; speedup vs baseline: 1.2054x; 1.0553x over previous
//
#include <hip/hip_runtime.h>

// Depthwise xcorr: out[p][oy][ox] = sum_{ky,kx} x[p][oy+ky][ox+kx] * z[p][ky][kx]
// 32768 planes. x: 31x31, z: 7x7, out: 25x25, fp32.
//
// Round 15: kill the LDS bank conflicts WITHOUT losing 16B staging.
// R14 post-mortem: LDS pipe = ~45us of the 70us kernel (21us base + 24us
// conflicts from packed stride-31). XOR swizzle col' = col ^ ((row&7)<<2)
// only flips bits >=2 -> every 4-aligned 16B chunk stays contiguous in BOTH
// LDS and global, so the swizzle composes with global_load_lds width=16
// (pre-swizzled source, linear LDS dest, swizzled read - both-sides rule).
//  - LPLANE = 1024 (pow2: staging math is shifts), stride-32 rows, row31 pad
//  - 128 thr, PPB=5 (125/128 lanes), LDS 21504 B -> 7 blocks/CU (14 waves)
//  - z in LDS (global-held zr spills: R7/R9), __launch_bounds__(128,2)
//  - tail tile: 4B-staged clamped path (a 16B chunk would cross XTOT)

#define PPB 5
#define WX 31
#define XPLANE 961
#define TDW (PPB * XPLANE)      // 4805 x dwords per tile
#define LPLANE 1024             // 32 rows x 32 cols (row 31 + col 31 = pad)
#define XREG (PPB * LPLANE)     // 5120 dwords
#define ZPLANE 49
#define ZDW (PPB * ZPLANE)      // 245
#define ZREG 256
#define OPLANE 625
#define WO 25

typedef __attribute__((address_space(1))) const void gaddr_t;
typedef __attribute__((address_space(3))) void laddr_t;

__global__ __launch_bounds__(128, 2) void dwxcorr_kernel(
    const float* __restrict__ z, const float* __restrict__ x,
    float* __restrict__ out, int nplanes) {
  __shared__ float lds[XREG + ZREG];  // 21504 B -> 7 blocks/CU

  const int tid = threadIdx.x;
  const int t = blockIdx.x;
  const int wb4 = (tid & ~63) * 4;    // wave-uniform dword base, 16B/lane
  const int wb1 = tid & ~63;          // wave-uniform dword base, 4B/lane
  const long XTOT = (long)nplanes * XPLANE;
  const long ZTOT = (long)nplanes * ZPLANE;
  const long xoff = (long)t * TDW;
  const long zoff = (long)t * ZDW;
  const long gz0 = zoff & ~3L;
  const int offz = (int)(zoff & 3);

  // LDS dword (p, row, c) holds x[p*961 + row*31 + (c ^ ((row&7)<<2))]
  if (xoff + TDW + 31 <= XTOT && gz0 + ZREG <= ZTOT) {
    // ---- fast path: 10 passes of 16B chunks, source pre-swizzled ----
#pragma unroll
    for (int c = 0; c < 10; ++c) {
      int s = c * 512 + tid * 4;       // 4-aligned LDS dword slot
      int p = s >> 10;
      int row = (s >> 5) & 31;         // 31 = pad row (dup, never read)
      int q = s & 31;                  // 4-aligned chunk col
      int qq = q ^ ((row & 7) << 2);   // still 4-aligned, <= 28
      long g = xoff + p * XPLANE + row * WX + qq;
      __builtin_amdgcn_global_load_lds((gaddr_t*)(x + g),
                                       (laddr_t*)&lds[c * 512 + wb4], 16, 0, 0);
    }
    if (tid < 63)                      // z: 252 dwords, linear
      __builtin_amdgcn_global_load_lds((gaddr_t*)(z + gz0 + tid * 4),
                                       (laddr_t*)&lds[XREG + wb4], 16, 0, 0);
  } else {
    // ---- tail tile (1 of 6554): 4B staging, everything clamped ----
#pragma unroll
    for (int c = 0; c < 40; ++c) {
      int s = c * 128 + tid;
      int p = s >> 10;
      int row = (s >> 5) & 31;
      int q = s & 31;
      int qq = q ^ ((row & 7) << 2);
      long g = xoff + p * XPLANE + row * WX + qq;
      if (g > XTOT - 1) g = XTOT - 1;  // dup, never read
      __builtin_amdgcn_global_load_lds((gaddr_t*)(x + g),
                                       (laddr_t*)&lds[c * 128 + wb1], 4, 0, 0);
    }
    if (tid < 63) {
      long gz = gz0 + tid * 4;
      if (gz > ZTOT - 4) gz = ZTOT - 4;
      __builtin_amdgcn_global_load_lds((gaddr_t*)(z + gz),
                                       (laddr_t*)&lds[XREG + wb4], 16, 0, 0);
    }
  }
  __syncthreads();  // single drain + barrier

  // ---- compute: thread -> (plane cpp, 5x5 tile (ty,tx)); 125/128 active ----
  const int p0 = t * PPB;
  const int pmax = min(PPB, nplanes - p0);
  const int cpp = tid / 25;
  if (tid >= PPB * 25 || cpp >= pmax) return;
  const int t25 = tid - cpp * 25;
  const int ty = t25 / 5;
  const int tx = t25 - ty * 5;
  const int tx5 = tx * 5;

  // z from LDS (compiler sinks reads to first use; broadcast, 3 banks/wave)
  const float* zb = &lds[XREG + offz + cpp * ZPLANE];
  float zr[ZPLANE];
#pragma unroll
  for (int j = 0; j < ZPLANE; ++j) zr[j] = zb[j];

  float acc[5][5];
#pragma unroll
  for (int r = 0; r < 5; ++r)
#pragma unroll
    for (int j = 0; j < 5; ++j) acc[r][j] = 0.0f;

  const float* pb = &lds[cpp * LPLANE];

  // Stream 11 patch rows; row iy feeds output rows orow = iy-ky in [0,4]
#pragma unroll
  for (int iy = 0; iy < 11; ++iy) {
    const int row = ty * 5 + iy;
    const int rb = row << 5;
    const int f = (row & 7) << 2;
    float xr[11];
#pragma unroll
    for (int k = 0; k < 11; ++k) xr[k] = pb[rb + ((tx5 + k) ^ f)];
    const int ky_lo = (iy - 4 < 0) ? 0 : iy - 4;
    const int ky_hi = (iy < 6) ? iy : 6;
#pragma unroll
    for (int ky = 0; ky < 7; ++ky) {
      if (ky < ky_lo || ky > ky_hi) continue;  // folds at compile time
      const int orow = iy - ky;
#pragma unroll
      for (int kx = 0; kx < 7; ++kx) {
        const float zv = zr[ky * 7 + kx];
#pragma unroll
        for (int j = 0; j < 5; ++j)
          acc[orow][j] = fmaf(xr[kx + j], zv, acc[orow][j]);
      }
    }
  }

  // ---- write the 5x5 tile ----
  float* ob = out + (long)(p0 + cpp) * OPLANE + (ty * 5) * WO + tx5;
#pragma unroll
  for (int r = 0; r < 5; ++r)
#pragma unroll
    for (int j = 0; j < 5; ++j) ob[r * WO + j] = acc[r][j];
}

extern "C" void kernel_launch(void* const* d_in, const int* in_sizes, int n_in,
                              void* d_out, int out_size, void* d_ws, size_t ws_size,
                              hipStream_t stream) {
  const float* z = (const float*)d_in[0];  // [B,C,7,7]
  const float* x = (const float*)d_in[1];  // [B,C,31,31]
  float* out = (float*)d_out;              // [B,C,25,25]

  const int nplanes = in_sizes[0] / ZPLANE;      // 32768
  const int blocks = (nplanes + PPB - 1) / PPB;  // 6554

  hipLaunchKernelGGL(dwxcorr_kernel, dim3(blocks), dim3(128), 0, stream,
                     z, x, out, nplanes);
}